// Round 7
// baseline (51.644 us; speedup 1.0000x reference)
//
#include <hip/hip_runtime.h>
#include <hip/hip_bf16.h>

#define BSZ 4096
#define NSZ 8192
#define DD  128
#define TILE 128
#define GROUPS 8
#define TPB 8     // col-tiles per block
#define C2 14.426950408889634f   // 10 * log2(e): exp(10*s) = exp2(s*C2)

typedef __attribute__((ext_vector_type(8))) short bf16x8;
typedef __attribute__((ext_vector_type(4))) float f32x4;

// ---------------- Kernel 1: normalize rows of reps=[zjs; zis] -> bf16 ----------------
__global__ __launch_bounds__(256)
void norm_kernel(const float* __restrict__ zis,
                 const float* __restrict__ zjs,
                 __hip_bfloat16* __restrict__ rn) {
    const int row  = blockIdx.x * 4 + (threadIdx.x >> 6);
    const int lane = threadIdx.x & 63;
    const float* src = (row < BSZ) ? (zjs + (size_t)row * DD)
                                   : (zis + (size_t)(row - BSZ) * DD);
    float2 v = *(const float2*)(src + lane * 2);
    float ss = v.x * v.x + v.y * v.y;
    #pragma unroll
    for (int off = 32; off; off >>= 1) ss += __shfl_xor(ss, off);
    float inv = 1.0f / fmaxf(sqrtf(ss), 1e-8f);
    __hip_bfloat16 a = __float2bfloat16(v.x * inv);
    __hip_bfloat16 b = __float2bfloat16(v.y * inv);
    ushort2 pk;
    pk.x = *(const ushort*)&a;
    pk.y = *(const ushort*)&b;
    *(ushort2*)(rn + (size_t)row * DD + lane * 2) = pk;
}

// ---------------- Kernel 2: barrier-free, LDS-free fused sim GEMM + exp + row sums ----
// grid (GROUPS, 64): bi = blockIdx.y (row tile), g = blockIdx.x; block loops over
// bj = g*TPB .. g*TPB+7. 256 threads = 4 waves in a 2x2 grid; wave (wm,wn) owns
// 64 rows x 64 cols. A-frags in registers for the whole block; B-frags loaded
// directly from global (rn is 2MB, L2-resident; fragment reads use full 64B
// lines). No LDS staging, no main-loop __syncthreads. Row-sums of exp(s/tau)
// accumulate in registers across all TPB tiles; block writes 128 per-row partials.
__global__ __launch_bounds__(256)
void sim_lse_kernel(const __hip_bfloat16* __restrict__ rn,
                    float* __restrict__ partials,
                    float* __restrict__ pos) {
    const int g   = blockIdx.x;
    const int bi  = blockIdx.y;
    const int tid = threadIdx.x;
    const int wid  = tid >> 6;
    const int lane = tid & 63;
    const int l15  = lane & 15;
    const int kg   = lane >> 4;        // 0..3
    const int wm   = wid >> 1;         // 0..1 row half
    const int wn   = wid & 1;          // 0..1 col half

    // ---- A fragments: 64 rows (this wave's wm half), in registers ----
    const char* abase = (const char*)rn + (size_t)(bi * TILE + wm * 64 + l15) * 256;
    bf16x8 af[4][4];
    #pragma unroll
    for (int mf = 0; mf < 4; ++mf)
        #pragma unroll
        for (int kk = 0; kk < 4; ++kk)
            af[mf][kk] = *(const bf16x8*)(abase + mf * 16 * 256 + kk * 64 + kg * 16);

    float rsum[4][4] = {};
    const int bjp = (bi + 32) & 63;

    for (int t = 0; t < TPB; ++t) {
        const int bj = g * TPB + t;
        const char* bbase = (const char*)rn
                          + (size_t)bj * TILE * 256 + (size_t)(wn * 64) * 256;
        const bool dglb = (bj == bi)  && (wm == wn);
        const bool pglb = (bj == bjp) && (wm == wn);

        #pragma unroll
        for (int nh = 0; nh < 2; ++nh) {
            // ---- load this half's B fragments straight from global (L2) ----
            bf16x8 bfr[2][4];
            #pragma unroll
            for (int nf2 = 0; nf2 < 2; ++nf2)
                #pragma unroll
                for (int kk = 0; kk < 4; ++kk)
                    bfr[nf2][kk] = *(const bf16x8*)(bbase
                        + (size_t)((nh * 2 + nf2) * 16 + l15) * 256 + kk * 64 + kg * 16);

            // ---- MFMA: 64 rows x 32 cols, K=128 ----
            f32x4 acc[4][2] = {};
            #pragma unroll
            for (int kk = 0; kk < 4; ++kk)
                #pragma unroll
                for (int mf = 0; mf < 4; ++mf)
                    #pragma unroll
                    for (int nf2 = 0; nf2 < 2; ++nf2)
                        acc[mf][nf2] = __builtin_amdgcn_mfma_f32_16x16x32_bf16(
                            af[mf][kk], bfr[nf2][kk], acc[mf][nf2], 0, 0, 0);

            // ---- lean epilogue: p = exp2(s*C2); rsum += p ----
            #pragma unroll
            for (int mf = 0; mf < 4; ++mf)
                #pragma unroll
                for (int nf2 = 0; nf2 < 2; ++nf2)
                    #pragma unroll
                    for (int reg = 0; reg < 4; ++reg)
                        rsum[mf][reg] += exp2f(acc[mf][nf2][reg] * C2);

            // ---- rare fixups (wave-uniform branches) ----
            if (dglb) {
                // subtract the self-term that the common path added
                #pragma unroll
                for (int nf2 = 0; nf2 < 2; ++nf2) {
                    const int mf = nh * 2 + nf2;   // diag frags have mf == nf
                    #pragma unroll
                    for (int reg = 0; reg < 4; ++reg)
                        if (kg * 4 + reg == l15)
                            rsum[mf][reg] -= exp2f(acc[mf][nf2][reg] * C2);
                }
            }
            if (pglb) {
                #pragma unroll
                for (int nf2 = 0; nf2 < 2; ++nf2) {
                    const int mf = nh * 2 + nf2;
                    #pragma unroll
                    for (int reg = 0; reg < 4; ++reg)
                        if (kg * 4 + reg == l15)
                            pos[bi * TILE + wm * 64 + mf * 16 + l15] = acc[mf][nf2][reg];
                }
            }
        }
    }

    // ---- row-sum reduce across the 16 l15-lanes; combine wn pairs via LDS ----
    __shared__ float red[2][64];
    #pragma unroll
    for (int mf = 0; mf < 4; ++mf)
        #pragma unroll
        for (int reg = 0; reg < 4; ++reg) {
            float v = rsum[mf][reg];
            v += __shfl_xor(v, 1);
            v += __shfl_xor(v, 2);
            v += __shfl_xor(v, 4);
            v += __shfl_xor(v, 8);
            rsum[mf][reg] = v;   // valid on l15==0 lanes
        }
    if (wn == 1 && l15 == 0) {
        #pragma unroll
        for (int mf = 0; mf < 4; ++mf)
            #pragma unroll
            for (int reg = 0; reg < 4; ++reg)
                red[wm][mf * 16 + kg * 4 + reg] = rsum[mf][reg];
    }
    __syncthreads();
    if (wn == 0 && l15 == 0) {
        #pragma unroll
        for (int mf = 0; mf < 4; ++mf)
            #pragma unroll
            for (int reg = 0; reg < 4; ++reg) {
                int lr = mf * 16 + kg * 4 + reg;
                partials[(size_t)g * NSZ + bi * TILE + wm * 64 + lr] =
                    rsum[mf][reg] + red[wm][lr];
            }
    }
}

// ---------------- Kernel 3: final scalar reduction ----------------
__global__ __launch_bounds__(1024)
void reduce_kernel(const float* __restrict__ partials,
                   const float* __restrict__ pos,
                   float* __restrict__ out) {
    int tid = threadIdx.x;  // 1024; 8 rows each
    int base = tid * 8;
    float se[8] = {0.f, 0.f, 0.f, 0.f, 0.f, 0.f, 0.f, 0.f};
    #pragma unroll
    for (int gr = 0; gr < GROUPS; ++gr) {
        const float* p = partials + (size_t)gr * NSZ + base;
        float4 a = *(const float4*)(p);
        float4 b = *(const float4*)(p + 4);
        se[0] += a.x; se[1] += a.y; se[2] += a.z; se[3] += a.w;
        se[4] += b.x; se[5] += b.y; se[6] += b.z; se[7] += b.w;
    }
    float ce = 0.f, pt = 0.f;
    #pragma unroll
    for (int h = 0; h < 2; ++h) {
        float4 p4 = *(const float4*)(pos + base + h * 4);
        const float* pp = (const float*)&p4;
        #pragma unroll
        for (int q = 0; q < 4; ++q) {
            float s = se[h * 4 + q];
            ce += __logf(s) - pp[q] * 10.0f;
            pt += exp2f(pp[q] * C2) / s;
        }
    }
    #pragma unroll
    for (int off = 32; off; off >>= 1) {
        ce += __shfl_xor(ce, off);
        pt += __shfl_xor(pt, off);
    }
    __shared__ float lce[16], lpt[16];
    if ((tid & 63) == 0) { lce[tid >> 6] = ce; lpt[tid >> 6] = pt; }
    __syncthreads();
    if (tid == 0) {
        float CE = 0.f, PT = 0.f;
        #pragma unroll
        for (int w = 0; w < 16; ++w) { CE += lce[w]; PT += lpt[w]; }
        float loss = CE / (float)NSZ + 1.0f
                   - PT * ((float)BSZ / ((float)NSZ * (float)(NSZ - 1)));
        out[0] = loss;
    }
}

extern "C" void kernel_launch(void* const* d_in, const int* in_sizes, int n_in,
                              void* d_out, int out_size, void* d_ws, size_t ws_size,
                              hipStream_t stream) {
    const float* zis = (const float*)d_in[0];
    const float* zjs = (const float*)d_in[1];
    float* out = (float*)d_out;

    char* ws = (char*)d_ws;
    __hip_bfloat16* rn = (__hip_bfloat16*)ws;                       // 2 MB
    float* partials = (float*)(ws + 2 * 1024 * 1024);               // 256 KB
    float* pos      = (float*)(ws + 2 * 1024 * 1024 + 256 * 1024);  // 32 KB

    norm_kernel<<<NSZ / 4, 256, 0, stream>>>(zis, zjs, rn);

    dim3 grid(GROUPS, 64);
    sim_lse_kernel<<<grid, 256, 0, stream>>>(rn, partials, pos);

    reduce_kernel<<<1, 1024, 0, stream>>>(partials, pos, out);
}